// Round 1
// baseline (7319.685 us; speedup 1.0000x reference)
//
#include <hip/hip_runtime.h>
#include <cstdint>
#include <cstddef>

#define NN 50000
#define EE 500000

// ---------------- workspace layout (float offsets) ----------------
static constexpr size_t OQ   = 0;                          // q    NN*64
static constexpr size_t OKk  = OQ   + (size_t)NN * 64;     // k    NN*64
static constexpr size_t OV   = OKk  + (size_t)NN * 64;     // v    NN*64
static constexpr size_t OSK  = OV   + (size_t)NN * 64;     // skip/conv NN*64
static constexpr size_t OACC = OSK  + (size_t)NN * 64;     // msg acc NN*64
static constexpr size_t OAL  = OACC + (size_t)NN * 64;     // alpha EE*4
static constexpr size_t OM   = OAL  + (size_t)EE * 4;      // max  NN*4 (uint)
static constexpr size_t ODEN = OM   + (size_t)NN * 4;      // denom NN*4
static constexpr size_t OBA  = ODEN + (size_t)NN * 4;      // x buf A NN*64
static constexpr size_t OBB  = OBA  + (size_t)NN * 64;     // x buf B NN*64
static constexpr size_t ORP  = OBB  + (size_t)NN * 64;     // rp EE
static constexpr size_t OST  = ORP  + (size_t)EE;          // dstats 4 doubles (8 floats)
static constexpr size_t OSTF = OST  + 8;                   // statsf 2 floats
static constexpr size_t OBN  = OSTF + 2;                   // bn sums 128 floats

// ---------------- helpers ----------------
__device__ __forceinline__ unsigned enc_f(float f) {
    unsigned u = __float_as_uint(f);
    return (u & 0x80000000u) ? ~u : (u | 0x80000000u);
}
__device__ __forceinline__ float dec_f(unsigned u) {
    unsigned b = (u & 0x80000000u) ? (u ^ 0x80000000u) : ~u;
    return __uint_as_float(b);
}

// out-row(64) = xv(1x64) * W(64x64, LDS) + b(LDS); chunked so all reg indices are compile-time
__device__ __forceinline__ void gemv64(const float (&xv)[64],
                                       const float* __restrict__ sW,
                                       const float* __restrict__ sb,
                                       float* __restrict__ dst) {
    for (int jch = 0; jch < 4; ++jch) {
        float ov[16];
#pragma unroll
        for (int jj = 0; jj < 16; ++jj) ov[jj] = sb[jch * 16 + jj];
#pragma unroll
        for (int kk = 0; kk < 64; ++kk) {
            float xk = xv[kk];
            const float* wr = sW + kk * 64 + jch * 16;
#pragma unroll
            for (int jj = 0; jj < 16; ++jj) ov[jj] = fmaf(xk, wr[jj], ov[jj]);
        }
        float4* pd = reinterpret_cast<float4*>(dst + jch * 16);
        pd[0] = make_float4(ov[0], ov[1], ov[2], ov[3]);
        pd[1] = make_float4(ov[4], ov[5], ov[6], ov[7]);
        pd[2] = make_float4(ov[8], ov[9], ov[10], ov[11]);
        pd[3] = make_float4(ov[12], ov[13], ov[14], ov[15]);
    }
}

// ---------------- kernels ----------------
__global__ void k_init(double* dstats) {
    if (threadIdx.x < 2) dstats[threadIdx.x] = 0.0;
}

__global__ __launch_bounds__(256) void k_rp(const float* __restrict__ x,
                                            const int* __restrict__ ei,
                                            float* __restrict__ rp,
                                            double* __restrict__ dstats) {
    int tid = threadIdx.x;
    size_t e = (size_t)blockIdx.x * 16 + (tid >> 4);
    int l = tid & 15;
    float ssum = 0.f;
    bool valid = e < (size_t)EE;
    if (valid) {
        size_t r = (size_t)ei[e], c = (size_t)ei[EE + e];
        float4 a = reinterpret_cast<const float4*>(x + r * 64)[l];
        float4 b = reinterpret_cast<const float4*>(x + c * 64)[l];
        float dx = a.x - b.x, dy = a.y - b.y, dz = a.z - b.z, dw = a.w - b.w;
        ssum = dx * dx + dy * dy + dz * dz + dw * dw;
    }
#pragma unroll
    for (int o = 1; o < 16; o <<= 1) ssum += __shfl_xor(ssum, o);
    float rv = sqrtf(ssum);
    float c1 = 0.f;
    if (valid && l == 0) { rp[e] = rv; c1 = rv; }
    float c2 = c1 * rv;
#pragma unroll
    for (int o = 16; o < 64; o <<= 1) { c1 += __shfl_xor(c1, o); c2 += __shfl_xor(c2, o); }
    __shared__ float s1[4], s2[4];
    if ((tid & 63) == 0) { s1[tid >> 6] = c1; s2[tid >> 6] = c2; }
    __syncthreads();
    if (tid == 0) {
        atomicAdd(dstats + 0, (double)(s1[0] + s1[1] + s1[2] + s1[3]));
        atomicAdd(dstats + 1, (double)(s2[0] + s2[1] + s2[2] + s2[3]));
    }
}

__global__ void k_statsf(const double* dstats, float* statsf) {
    if (threadIdx.x == 0 && blockIdx.x == 0) {
        double s = dstats[0], q = dstats[1];
        double mean = s / (double)EE;
        double var = (q - (double)EE * mean * mean) / (double)(EE - 1);
        if (var < 0) var = 0;
        double sd = sqrt(var);
        statsf[0] = (float)mean;
        statsf[1] = (float)(1.0 / (sd + 1e-6));
    }
}

__global__ __launch_bounds__(256) void k_mlp(const float* __restrict__ ea,
                                             const float* __restrict__ W1, const float* __restrict__ b1,
                                             const float* __restrict__ W2, const float* __restrict__ b2,
                                             const float* __restrict__ rp, const float* __restrict__ statsf,
                                             float* __restrict__ eout) {
    __shared__ float sW1[4096], sW2[4096], sb1[64], sb2[64];
    int tid = threadIdx.x;
    for (int i = tid; i < 4096; i += 256) { sW1[i] = W1[i]; sW2[i] = W2[i]; }
    if (tid < 64) { sb1[tid] = b1[tid]; sb2[tid] = b2[tid]; }
    __syncthreads();
    size_t e = (size_t)blockIdx.x * 256 + tid;
    if (e >= (size_t)EE) return;

    float xv[64];
    const float4* px = reinterpret_cast<const float4*>(ea + e * 64);
#pragma unroll
    for (int i = 0; i < 16; ++i) {
        float4 t = px[i];
        xv[4 * i] = t.x; xv[4 * i + 1] = t.y; xv[4 * i + 2] = t.z; xv[4 * i + 3] = t.w;
    }
    float ov[64];
#pragma unroll
    for (int j = 0; j < 64; ++j) ov[j] = sb2[j];
    for (int ch = 0; ch < 4; ++ch) {
        float hc[16];
#pragma unroll
        for (int t = 0; t < 16; ++t) hc[t] = sb1[ch * 16 + t];
#pragma unroll
        for (int kk = 0; kk < 64; ++kk) {
            float xk = xv[kk];
            const float* wr = sW1 + kk * 64 + ch * 16;
#pragma unroll
            for (int t = 0; t < 16; ++t) hc[t] = fmaf(xk, wr[t], hc[t]);
        }
#pragma unroll
        for (int t = 0; t < 16; ++t) hc[t] = fmaxf(hc[t], 0.f);
#pragma unroll
        for (int t = 0; t < 16; ++t) {
            float hk = hc[t];
            const float* wr = sW2 + (ch * 16 + t) * 64;
#pragma unroll
            for (int j = 0; j < 64; ++j) ov[j] = fmaf(hk, wr[j], ov[j]);
        }
    }
    float rps = (rp[e] - statsf[0]) * statsf[1];
    float4* pd = reinterpret_cast<float4*>(eout + e * 64);
#pragma unroll
    for (int i = 0; i < 16; ++i)
        pd[i] = make_float4(ov[4 * i] + rps, ov[4 * i + 1] + rps, ov[4 * i + 2] + rps, ov[4 * i + 3] + rps);
}

__global__ void k_zero(float* acc, float* den, unsigned* mint, float* bn) {
    size_t idx = (size_t)blockIdx.x * blockDim.x + threadIdx.x;
    size_t stride = (size_t)gridDim.x * blockDim.x;
    for (size_t i = idx; i < (size_t)NN * 64; i += stride) acc[i] = 0.f;
    for (size_t i = idx; i < (size_t)NN * 4; i += stride) { den[i] = 0.f; mint[i] = 0x00800000u; }
    if (idx < 128) bn[idx] = 0.f;
}

__global__ __launch_bounds__(256) void k_node(const float* __restrict__ xin,
                                              const float* __restrict__ Wq, const float* __restrict__ bq,
                                              const float* __restrict__ Wk, const float* __restrict__ bk,
                                              const float* __restrict__ Wv, const float* __restrict__ bv,
                                              const float* __restrict__ Wsk, const float* __restrict__ bsk,
                                              float* __restrict__ q, float* __restrict__ k,
                                              float* __restrict__ v, float* __restrict__ sk) {
    __shared__ float sA[4096], sB[4096], sba[64], sbb[64];
    int tid = threadIdx.x;
    size_t node = (size_t)blockIdx.x * 256 + tid;
    bool ok = node < (size_t)NN;
    float xv[64];
    if (ok) {
        const float4* px = reinterpret_cast<const float4*>(xin + node * 64);
#pragma unroll
        for (int i = 0; i < 16; ++i) {
            float4 t = px[i];
            xv[4 * i] = t.x; xv[4 * i + 1] = t.y; xv[4 * i + 2] = t.z; xv[4 * i + 3] = t.w;
        }
    }
    for (int i = tid; i < 4096; i += 256) { sA[i] = Wq[i]; sB[i] = Wk[i]; }
    if (tid < 64) { sba[tid] = bq[tid]; sbb[tid] = bk[tid]; }
    __syncthreads();
    if (ok) { gemv64(xv, sA, sba, q + node * 64); gemv64(xv, sB, sbb, k + node * 64); }
    __syncthreads();
    for (int i = tid; i < 4096; i += 256) { sA[i] = Wv[i]; sB[i] = Wsk[i]; }
    if (tid < 64) { sba[tid] = bv[tid]; sbb[tid] = bsk[tid]; }
    __syncthreads();
    if (ok) { gemv64(xv, sA, sba, v + node * 64); gemv64(xv, sB, sbb, sk + node * 64); }
}

__global__ __launch_bounds__(256) void k_alpha(const int* __restrict__ ei,
                                               const float* __restrict__ eptr,
                                               const float* __restrict__ Wep,
                                               const float* __restrict__ q, const float* __restrict__ k,
                                               float* __restrict__ alpha, unsigned* __restrict__ mint) {
    __shared__ float sWe[4096];
    int tid = threadIdx.x;
    for (int i = tid; i < 4096; i += 256) sWe[i] = Wep[i];
    __syncthreads();
    size_t e = (size_t)blockIdx.x * 256 + tid;
    if (e >= (size_t)EE) return;
    size_t r = (size_t)ei[e], c = (size_t)ei[EE + e];
    float ev[64];
    const float4* pe = reinterpret_cast<const float4*>(eptr + e * 64);
#pragma unroll
    for (int i = 0; i < 16; ++i) {
        float4 t = pe[i];
        ev[4 * i] = t.x; ev[4 * i + 1] = t.y; ev[4 * i + 2] = t.z; ev[4 * i + 3] = t.w;
    }
    for (int h = 0; h < 4; ++h) {
        float eeh[16];
#pragma unroll
        for (int cc = 0; cc < 16; ++cc) eeh[cc] = 0.f;
#pragma unroll
        for (int kk = 0; kk < 64; ++kk) {
            float ek = ev[kk];
            const float* wr = sWe + kk * 64 + h * 16;
#pragma unroll
            for (int cc = 0; cc < 16; ++cc) eeh[cc] = fmaf(ek, wr[cc], eeh[cc]);
        }
        const float4* pq = reinterpret_cast<const float4*>(q + c * 64 + h * 16);
        const float4* pk = reinterpret_cast<const float4*>(k + r * 64 + h * 16);
        float acc = 0.f;
#pragma unroll
        for (int i = 0; i < 4; ++i) {
            float4 qv = pq[i], kv = pk[i];
            acc += qv.x * (kv.x + eeh[4 * i + 0]) + qv.y * (kv.y + eeh[4 * i + 1]) +
                   qv.z * (kv.z + eeh[4 * i + 2]) + qv.w * (kv.w + eeh[4 * i + 3]);
        }
        float a = acc * 0.25f;
        alpha[e * 4 + h] = a;
        atomicMax(mint + c * 4 + h, enc_f(a));
    }
}

__global__ __launch_bounds__(256) void k_msg(const int* __restrict__ ei,
                                             const float* __restrict__ eptr,
                                             const float* __restrict__ Wep,
                                             const float* __restrict__ v,
                                             const float* __restrict__ alpha,
                                             const unsigned* __restrict__ mint,
                                             float* __restrict__ den, float* __restrict__ acc) {
    __shared__ float sWe[4096];
    int tid = threadIdx.x;
    for (int i = tid; i < 4096; i += 256) sWe[i] = Wep[i];
    __syncthreads();
    size_t e = (size_t)blockIdx.x * 256 + tid;
    if (e >= (size_t)EE) return;
    size_t r = (size_t)ei[e], c = (size_t)ei[EE + e];
    float ev[64];
    const float4* pe = reinterpret_cast<const float4*>(eptr + e * 64);
#pragma unroll
    for (int i = 0; i < 16; ++i) {
        float4 t = pe[i];
        ev[4 * i] = t.x; ev[4 * i + 1] = t.y; ev[4 * i + 2] = t.z; ev[4 * i + 3] = t.w;
    }
    for (int h = 0; h < 4; ++h) {
        float mh = dec_f(mint[c * 4 + h]);
        float a = expf(alpha[e * 4 + h] - mh);
        atomicAdd(den + c * 4 + h, a);
        float eeh[16];
#pragma unroll
        for (int cc = 0; cc < 16; ++cc) eeh[cc] = 0.f;
#pragma unroll
        for (int kk = 0; kk < 64; ++kk) {
            float ek = ev[kk];
            const float* wr = sWe + kk * 64 + h * 16;
#pragma unroll
            for (int cc = 0; cc < 16; ++cc) eeh[cc] = fmaf(ek, wr[cc], eeh[cc]);
        }
        const float4* pv = reinterpret_cast<const float4*>(v + r * 64 + h * 16);
        float* ab = acc + c * 64 + h * 16;
#pragma unroll
        for (int i = 0; i < 4; ++i) {
            float4 vv = pv[i];
            atomicAdd(ab + 4 * i + 0, a * (vv.x + eeh[4 * i + 0]));
            atomicAdd(ab + 4 * i + 1, a * (vv.y + eeh[4 * i + 1]));
            atomicAdd(ab + 4 * i + 2, a * (vv.z + eeh[4 * i + 2]));
            atomicAdd(ab + 4 * i + 3, a * (vv.w + eeh[4 * i + 3]));
        }
    }
}

__global__ __launch_bounds__(256) void k_combine(const float* __restrict__ acc,
                                                 const float* __restrict__ den,
                                                 const float* __restrict__ sk,
                                                 float* __restrict__ outb,
                                                 float* __restrict__ bn, int do_bn) {
    int tid = threadIdx.x;
    size_t idx0 = (size_t)blockIdx.x * 256 + tid;
    size_t stride = (size_t)gridDim.x * 256;
    float s = 0.f, ss = 0.f;
    for (size_t i = idx0; i < (size_t)NN * 64; i += stride) {
        size_t n = i >> 6;
        int d = (int)(i & 63);
        int h = d >> 4;
        float val = acc[i] / (den[n * 4 + h] + 1e-16f) + sk[i];
        outb[i] = val;
        s += val; ss += val * val;
    }
    if (do_bn) {
        __shared__ float l1[256], l2[256];
        l1[tid] = s; l2[tid] = ss;
        __syncthreads();
        if (tid < 64) {
            float a = l1[tid] + l1[tid + 64] + l1[tid + 128] + l1[tid + 192];
            float b = l2[tid] + l2[tid + 64] + l2[tid + 128] + l2[tid + 192];
            atomicAdd(bn + tid, a);
            atomicAdd(bn + 64 + tid, b);
        }
    }
}

__global__ __launch_bounds__(256) void k_bnln(const float* __restrict__ conv,
                                              const float* __restrict__ xres,
                                              const float* __restrict__ bn,
                                              const float* __restrict__ g, const float* __restrict__ b,
                                              const float* __restrict__ lg, const float* __restrict__ lb,
                                              float* __restrict__ xout) {
    int tid = threadIdx.x;
    int lane = tid & 63;
    size_t row = (size_t)blockIdx.x * 4 + (tid >> 6);
    if (row >= (size_t)NN) return;
    float val = conv[row * 64 + lane];
    float mu = bn[lane] * (1.f / NN);
    float var = bn[64 + lane] * (1.f / NN) - mu * mu;
    float hn = (val - mu) * rsqrtf(var + 1e-5f) * g[lane] + b[lane];
    hn = fmaxf(hn, 0.f);
    float t = hn + xres[row * 64 + lane];
    float s = t, ss = t * t;
#pragma unroll
    for (int o = 32; o >= 1; o >>= 1) { s += __shfl_xor(s, o); ss += __shfl_xor(ss, o); }
    float mu2 = s * (1.f / 64.f);
    float var2 = ss * (1.f / 64.f) - mu2 * mu2;
    xout[row * 64 + lane] = (t - mu2) * rsqrtf(var2 + 1e-5f) * lg[lane] + lb[lane];
}

// ---------------- launch ----------------
extern "C" void kernel_launch(void* const* d_in, const int* in_sizes, int n_in,
                              void* d_out, int out_size, void* d_ws, size_t ws_size,
                              hipStream_t stream) {
    (void)in_sizes; (void)n_in; (void)out_size; (void)ws_size;
    const float* x   = (const float*)d_in[0];
    const int*   ei  = (const int*)d_in[1];
    const float* ea  = (const float*)d_in[2];
    const float* Wq  = (const float*)d_in[3];  const float* bq = (const float*)d_in[4];
    const float* Wk  = (const float*)d_in[5];  const float* bk = (const float*)d_in[6];
    const float* Wv  = (const float*)d_in[7];  const float* bv = (const float*)d_in[8];
    const float* We  = (const float*)d_in[9];
    const float* Wsk = (const float*)d_in[10]; const float* bsk = (const float*)d_in[11];
    const float* eW1 = (const float*)d_in[12]; const float* eb1 = (const float*)d_in[13];
    const float* eW2 = (const float*)d_in[14]; const float* eb2 = (const float*)d_in[15];
    const float* bng = (const float*)d_in[16]; const float* bnb = (const float*)d_in[17];
    const float* lng = (const float*)d_in[18]; const float* lnb = (const float*)d_in[19];

    float* ws = (float*)d_ws;
    float* out_x = (float*)d_out;
    float* out_e = out_x + (size_t)NN * 64;

    float* q   = ws + OQ;
    float* k   = ws + OKk;
    float* v   = ws + OV;
    float* sk  = ws + OSK;
    float* acc = ws + OACC;
    float* al  = ws + OAL;
    unsigned* mint = (unsigned*)(ws + OM);
    float* den = ws + ODEN;
    float* bufA = ws + OBA;
    float* bufB = ws + OBB;
    float* rp  = ws + ORP;
    double* dstats = (double*)(ws + OST);
    float* statsf = ws + OSTF;
    float* bn  = ws + OBN;

    k_init<<<1, 64, 0, stream>>>(dstats);
    k_rp<<<(EE + 15) / 16, 256, 0, stream>>>(x, ei, rp, dstats);
    k_statsf<<<1, 1, 0, stream>>>(dstats, statsf);
    k_mlp<<<(EE + 255) / 256, 256, 0, stream>>>(ea, eW1, eb1, eW2, eb2, rp, statsf, out_e);

    const float* xin = x;
    for (int l = 0; l < 3; ++l) {
        k_zero<<<2048, 256, 0, stream>>>(acc, den, mint, bn);
        k_node<<<(NN + 255) / 256, 256, 0, stream>>>(xin,
            Wq + (size_t)l * 4096, bq + (size_t)l * 64,
            Wk + (size_t)l * 4096, bk + (size_t)l * 64,
            Wv + (size_t)l * 4096, bv + (size_t)l * 64,
            Wsk + (size_t)l * 4096, bsk + (size_t)l * 64,
            q, k, v, sk);
        k_alpha<<<(EE + 255) / 256, 256, 0, stream>>>(ei, out_e, We + (size_t)l * 4096, q, k, al, mint);
        k_msg<<<(EE + 255) / 256, 256, 0, stream>>>(ei, out_e, We + (size_t)l * 4096, v, al, mint, den, acc);
        float* conv = (l == 2) ? out_x : sk;
        k_combine<<<2048, 256, 0, stream>>>(acc, den, sk, conv, bn, (l < 2) ? 1 : 0);
        if (l < 2) {
            float* xout = (l == 0) ? bufA : bufB;
            k_bnln<<<(NN + 3) / 4, 256, 0, stream>>>(conv, xin, bn,
                bng + (size_t)l * 64, bnb + (size_t)l * 64,
                lng + (size_t)l * 64, lnb + (size_t)l * 64, xout);
            xin = xout;
        }
    }
}

// Round 2
// 1960.472 us; speedup vs baseline: 3.7336x; 3.7336x over previous
//
#include <hip/hip_runtime.h>
#include <cstdint>
#include <cstddef>

#define NN 50000
#define EE 500000

// ---------------- workspace layout (float offsets) ----------------
static constexpr size_t NF   = (size_t)NN * 64;            // 3.2M
static constexpr size_t OQ   = 0;                          // q    NN*64
static constexpr size_t OKk  = OQ   + NF;                  // k    NN*64
static constexpr size_t OV   = OKk  + NF;                  // v    NN*64
static constexpr size_t OSK  = OV   + NF;                  // skip/conv NN*64
static constexpr size_t OBA  = OSK  + NF;                  // x buf A
static constexpr size_t OBB  = OBA  + NF;                  // x buf B
static constexpr size_t ORP  = OBB  + NF;                  // rp EE
static constexpr size_t OST  = ORP  + (size_t)EE;          // dstats 2 doubles
static constexpr size_t OSTF = OST  + 8;                   // statsf 2 floats
static constexpr size_t OBN  = OSTF + 2;                   // bn sums 128 floats
static constexpr size_t OI   = OBN  + 128;                 // int area (even)
static constexpr size_t ODEG = OI;                         // deg NN
static constexpr size_t OOFF = ODEG + NN;                  // off NN+1 (+1 pad)
static constexpr size_t OCNT = OOFF + NN + 2;              // cnt NN
static constexpr size_t OEL  = OCNT + NN;                  // elist EE int2

// out-row(64) = xv(1x64) * W(64x64, LDS) + b(LDS)
__device__ __forceinline__ void gemv64(const float (&xv)[64],
                                       const float* __restrict__ sW,
                                       const float* __restrict__ sb,
                                       float* __restrict__ dst) {
    for (int jch = 0; jch < 4; ++jch) {
        float ov[16];
#pragma unroll
        for (int jj = 0; jj < 16; ++jj) ov[jj] = sb[jch * 16 + jj];
#pragma unroll
        for (int kk = 0; kk < 64; ++kk) {
            float xk = xv[kk];
            const float* wr = sW + kk * 64 + jch * 16;
#pragma unroll
            for (int jj = 0; jj < 16; ++jj) ov[jj] = fmaf(xk, wr[jj], ov[jj]);
        }
        float4* pd = reinterpret_cast<float4*>(dst + jch * 16);
        pd[0] = make_float4(ov[0], ov[1], ov[2], ov[3]);
        pd[1] = make_float4(ov[4], ov[5], ov[6], ov[7]);
        pd[2] = make_float4(ov[8], ov[9], ov[10], ov[11]);
        pd[3] = make_float4(ov[12], ov[13], ov[14], ov[15]);
    }
}

// ---------------- misc kernels ----------------
__global__ void k_init(double* dstats) {
    if (threadIdx.x < 2) dstats[threadIdx.x] = 0.0;
}

__global__ __launch_bounds__(256) void k_rp(const float* __restrict__ x,
                                            const int* __restrict__ ei,
                                            float* __restrict__ rp,
                                            double* __restrict__ dstats) {
    int tid = threadIdx.x;
    size_t e = (size_t)blockIdx.x * 16 + (tid >> 4);
    int l = tid & 15;
    float ssum = 0.f;
    bool valid = e < (size_t)EE;
    if (valid) {
        size_t r = (size_t)ei[e], c = (size_t)ei[EE + e];
        float4 a = reinterpret_cast<const float4*>(x + r * 64)[l];
        float4 b = reinterpret_cast<const float4*>(x + c * 64)[l];
        float dx = a.x - b.x, dy = a.y - b.y, dz = a.z - b.z, dw = a.w - b.w;
        ssum = dx * dx + dy * dy + dz * dz + dw * dw;
    }
#pragma unroll
    for (int o = 1; o < 16; o <<= 1) ssum += __shfl_xor(ssum, o);
    float rv = sqrtf(ssum);
    float c1 = 0.f;
    if (valid && l == 0) { rp[e] = rv; c1 = rv; }
    float c2 = c1 * rv;
#pragma unroll
    for (int o = 16; o < 64; o <<= 1) { c1 += __shfl_xor(c1, o); c2 += __shfl_xor(c2, o); }
    __shared__ float s1[4], s2[4];
    if ((tid & 63) == 0) { s1[tid >> 6] = c1; s2[tid >> 6] = c2; }
    __syncthreads();
    if (tid == 0) {
        atomicAdd(dstats + 0, (double)(s1[0] + s1[1] + s1[2] + s1[3]));
        atomicAdd(dstats + 1, (double)(s2[0] + s2[1] + s2[2] + s2[3]));
    }
}

__global__ void k_statsf(const double* dstats, float* statsf) {
    if (threadIdx.x == 0 && blockIdx.x == 0) {
        double s = dstats[0], q = dstats[1];
        double mean = s / (double)EE;
        double var = (q - (double)EE * mean * mean) / (double)(EE - 1);
        if (var < 0) var = 0;
        double sd = sqrt(var);
        statsf[0] = (float)mean;
        statsf[1] = (float)(1.0 / (sd + 1e-6));
    }
}

__global__ __launch_bounds__(256) void k_mlp(const float* __restrict__ ea,
                                             const float* __restrict__ W1, const float* __restrict__ b1,
                                             const float* __restrict__ W2, const float* __restrict__ b2,
                                             const float* __restrict__ rp, const float* __restrict__ statsf,
                                             float* __restrict__ eout) {
    __shared__ float sW1[4096], sW2[4096], sb1[64], sb2[64];
    int tid = threadIdx.x;
    for (int i = tid; i < 4096; i += 256) { sW1[i] = W1[i]; sW2[i] = W2[i]; }
    if (tid < 64) { sb1[tid] = b1[tid]; sb2[tid] = b2[tid]; }
    __syncthreads();
    size_t e = (size_t)blockIdx.x * 256 + tid;
    if (e >= (size_t)EE) return;

    float xv[64];
    const float4* px = reinterpret_cast<const float4*>(ea + e * 64);
#pragma unroll
    for (int i = 0; i < 16; ++i) {
        float4 t = px[i];
        xv[4 * i] = t.x; xv[4 * i + 1] = t.y; xv[4 * i + 2] = t.z; xv[4 * i + 3] = t.w;
    }
    float ov[64];
#pragma unroll
    for (int j = 0; j < 64; ++j) ov[j] = sb2[j];
    for (int ch = 0; ch < 4; ++ch) {
        float hc[16];
#pragma unroll
        for (int t = 0; t < 16; ++t) hc[t] = sb1[ch * 16 + t];
#pragma unroll
        for (int kk = 0; kk < 64; ++kk) {
            float xk = xv[kk];
            const float* wr = sW1 + kk * 64 + ch * 16;
#pragma unroll
            for (int t = 0; t < 16; ++t) hc[t] = fmaf(xk, wr[t], hc[t]);
        }
#pragma unroll
        for (int t = 0; t < 16; ++t) hc[t] = fmaxf(hc[t], 0.f);
#pragma unroll
        for (int t = 0; t < 16; ++t) {
            float hk = hc[t];
            const float* wr = sW2 + (ch * 16 + t) * 64;
#pragma unroll
            for (int j = 0; j < 64; ++j) ov[j] = fmaf(hk, wr[j], ov[j]);
        }
    }
    float rps = (rp[e] - statsf[0]) * statsf[1];
    float4* pd = reinterpret_cast<float4*>(eout + e * 64);
#pragma unroll
    for (int i = 0; i < 16; ++i)
        pd[i] = make_float4(ov[4 * i] + rps, ov[4 * i + 1] + rps, ov[4 * i + 2] + rps, ov[4 * i + 3] + rps);
}

// ---------------- CSR build ----------------
__global__ void k_zint(int* deg, int* cnt) {
    int i = blockIdx.x * 256 + threadIdx.x;
    if (i < NN) { deg[i] = 0; cnt[i] = 0; }
}

__global__ void k_deg(const int* __restrict__ ei, int* __restrict__ deg) {
    int e = blockIdx.x * 256 + threadIdx.x;
    if (e < EE) atomicAdd(&deg[ei[EE + e]], 1);
}

__global__ __launch_bounds__(1024) void k_scan(const int* __restrict__ deg, int* __restrict__ off) {
    __shared__ int part[1024];
    int t = threadIdx.x;
    const int chunk = (NN + 1023) / 1024;  // 49
    int lo = t * chunk, hi = min(lo + chunk, NN);
    int s = 0;
    for (int i = lo; i < hi; ++i) s += deg[i];
    part[t] = s;
    __syncthreads();
    for (int o = 1; o < 1024; o <<= 1) {
        int v = (t >= o) ? part[t - o] : 0;
        __syncthreads();
        part[t] += v;
        __syncthreads();
    }
    int base = (t == 0) ? 0 : part[t - 1];
    for (int i = lo; i < hi; ++i) { off[i] = base; base += deg[i]; }
    if (t == 0) off[NN] = EE;
}

__global__ void k_scatter(const int* __restrict__ ei, const int* __restrict__ off,
                          int* __restrict__ cnt, int2* __restrict__ elist) {
    int e = blockIdx.x * 256 + threadIdx.x;
    if (e >= EE) return;
    int r = ei[e], c = ei[EE + e];
    int pos = off[c] + atomicAdd(&cnt[c], 1);
    elist[pos] = make_int2(e, r);
}

// ---------------- node-side GEMVs ----------------
__global__ __launch_bounds__(256) void k_node(const float* __restrict__ xin,
                                              const float* __restrict__ Wq, const float* __restrict__ bq,
                                              const float* __restrict__ Wk, const float* __restrict__ bk,
                                              const float* __restrict__ Wv, const float* __restrict__ bv,
                                              const float* __restrict__ Wsk, const float* __restrict__ bsk,
                                              float* __restrict__ q, float* __restrict__ k,
                                              float* __restrict__ v, float* __restrict__ sk) {
    __shared__ float sA[4096], sB[4096], sba[64], sbb[64];
    int tid = threadIdx.x;
    size_t node = (size_t)blockIdx.x * 256 + tid;
    bool ok = node < (size_t)NN;
    float xv[64];
    if (ok) {
        const float4* px = reinterpret_cast<const float4*>(xin + node * 64);
#pragma unroll
        for (int i = 0; i < 16; ++i) {
            float4 t = px[i];
            xv[4 * i] = t.x; xv[4 * i + 1] = t.y; xv[4 * i + 2] = t.z; xv[4 * i + 3] = t.w;
        }
    }
    for (int i = tid; i < 4096; i += 256) { sA[i] = Wq[i]; sB[i] = Wk[i]; }
    if (tid < 64) { sba[tid] = bq[tid]; sbb[tid] = bk[tid]; }
    __syncthreads();
    if (ok) { gemv64(xv, sA, sba, q + node * 64); gemv64(xv, sB, sbb, k + node * 64); }
    __syncthreads();
    for (int i = tid; i < 4096; i += 256) { sA[i] = Wv[i]; sB[i] = Wsk[i]; }
    if (tid < 64) { sba[tid] = bv[tid]; sbb[tid] = bsk[tid]; }
    __syncthreads();
    if (ok) { gemv64(xv, sA, sba, v + node * 64); gemv64(xv, sB, sbb, sk + node * 64); }
}

// ---------------- fused per-destination attention (online softmax) ----------------
// one wave per destination node; lane l owns output column l.
__global__ __launch_bounds__(256) void k_edge(const int* __restrict__ off,
                                              const int2* __restrict__ elist,
                                              const float* __restrict__ eptr,
                                              const float* __restrict__ Wep,
                                              const float* __restrict__ q,
                                              const float* __restrict__ k,
                                              const float* __restrict__ v,
                                              const float* __restrict__ skp,
                                              float* __restrict__ outb) {
    int lane = threadIdx.x & 63;
    size_t node = (size_t)blockIdx.x * 4 + (threadIdx.x >> 6);
    if (node >= (size_t)NN) return;

    // We column `lane` in registers (loop-invariant; L2-hot: 16KB shared by all waves)
    float wcol[64];
#pragma unroll
    for (int kk = 0; kk < 64; ++kk) wcol[kk] = Wep[kk * 64 + lane];

    float qv = q[node * 64 + lane];
    int p0 = off[node], p1 = off[node + 1];

    float m = -INFINITY, s = 0.f, o = 0.f;
    for (int p = p0; p < p1; ++p) {
        int2 pr = elist[p];              // wave-uniform load
        size_t e = (size_t)pr.x, r = (size_t)pr.y;
        float ev = eptr[e * 64 + lane];
        float kv = k[r * 64 + lane];
        float vv = v[r * 64 + lane];
        // ee[lane] = sum_k e[k] * We[k][lane]; e[k] broadcast via readlane
        float ee = 0.f;
#pragma unroll
        for (int kk = 0; kk < 64; ++kk) {
            float ek = __uint_as_float(__builtin_amdgcn_readlane(__float_as_uint(ev), kk));
            ee = fmaf(ek, wcol[kk], ee);
        }
        float d = qv * (kv + ee);
        d += __shfl_xor(d, 1); d += __shfl_xor(d, 2);
        d += __shfl_xor(d, 4); d += __shfl_xor(d, 8);
        float alpha = d * 0.25f;         // /sqrt(16)
        float mn = fmaxf(m, alpha);
        float sc = __expf(m - mn);       // exp(-inf)=0 on first edge
        float pt = __expf(alpha - mn);
        s = s * sc + pt;
        o = o * sc + pt * (vv + ee);
        m = mn;
    }
    float res = o / (s + 1e-16f) + skp[node * 64 + lane];
    outb[node * 64 + lane] = res;
}

// ---------------- BN stats + BN/ReLU/residual/LN ----------------
__global__ void k_zbn(float* bn) {
    if (threadIdx.x < 128) bn[threadIdx.x] = 0.f;
}

__global__ __launch_bounds__(256) void k_bnstat(const float* __restrict__ conv, float* __restrict__ bn) {
    int tid = threadIdx.x;
    size_t idx0 = (size_t)blockIdx.x * 256 + tid;
    size_t stride = (size_t)gridDim.x * 256;   // multiple of 64 -> column constant per thread
    float s = 0.f, ss = 0.f;
    for (size_t i = idx0; i < NF; i += stride) {
        float val = conv[i];
        s += val; ss += val * val;
    }
    __shared__ float l1[256], l2[256];
    l1[tid] = s; l2[tid] = ss;
    __syncthreads();
    if (tid < 64) {
        float a = l1[tid] + l1[tid + 64] + l1[tid + 128] + l1[tid + 192];
        float b = l2[tid] + l2[tid + 64] + l2[tid + 128] + l2[tid + 192];
        atomicAdd(bn + tid, a);
        atomicAdd(bn + 64 + tid, b);
    }
}

__global__ __launch_bounds__(256) void k_bnln(const float* __restrict__ conv,
                                              const float* __restrict__ xres,
                                              const float* __restrict__ bn,
                                              const float* __restrict__ g, const float* __restrict__ b,
                                              const float* __restrict__ lg, const float* __restrict__ lb,
                                              float* __restrict__ xout) {
    int tid = threadIdx.x;
    int lane = tid & 63;
    size_t row = (size_t)blockIdx.x * 4 + (tid >> 6);
    if (row >= (size_t)NN) return;
    float val = conv[row * 64 + lane];
    float mu = bn[lane] * (1.f / NN);
    float var = bn[64 + lane] * (1.f / NN) - mu * mu;
    float hn = (val - mu) * rsqrtf(var + 1e-5f) * g[lane] + b[lane];
    hn = fmaxf(hn, 0.f);
    float t = hn + xres[row * 64 + lane];
    float s = t, ss = t * t;
#pragma unroll
    for (int o = 32; o >= 1; o >>= 1) { s += __shfl_xor(s, o); ss += __shfl_xor(ss, o); }
    float mu2 = s * (1.f / 64.f);
    float var2 = ss * (1.f / 64.f) - mu2 * mu2;
    xout[row * 64 + lane] = (t - mu2) * rsqrtf(var2 + 1e-5f) * lg[lane] + lb[lane];
}

// ---------------- launch ----------------
extern "C" void kernel_launch(void* const* d_in, const int* in_sizes, int n_in,
                              void* d_out, int out_size, void* d_ws, size_t ws_size,
                              hipStream_t stream) {
    (void)in_sizes; (void)n_in; (void)out_size; (void)ws_size;
    const float* x   = (const float*)d_in[0];
    const int*   ei  = (const int*)d_in[1];
    const float* ea  = (const float*)d_in[2];
    const float* Wq  = (const float*)d_in[3];  const float* bq = (const float*)d_in[4];
    const float* Wk  = (const float*)d_in[5];  const float* bk = (const float*)d_in[6];
    const float* Wv  = (const float*)d_in[7];  const float* bv = (const float*)d_in[8];
    const float* We  = (const float*)d_in[9];
    const float* Wsk = (const float*)d_in[10]; const float* bsk = (const float*)d_in[11];
    const float* eW1 = (const float*)d_in[12]; const float* eb1 = (const float*)d_in[13];
    const float* eW2 = (const float*)d_in[14]; const float* eb2 = (const float*)d_in[15];
    const float* bng = (const float*)d_in[16]; const float* bnb = (const float*)d_in[17];
    const float* lng = (const float*)d_in[18]; const float* lnb = (const float*)d_in[19];

    float* ws = (float*)d_ws;
    float* out_x = (float*)d_out;
    float* out_e = out_x + NF;

    float* q    = ws + OQ;
    float* k    = ws + OKk;
    float* v    = ws + OV;
    float* sk   = ws + OSK;
    float* bufA = ws + OBA;
    float* bufB = ws + OBB;
    float* rp   = ws + ORP;
    double* dstats = (double*)(ws + OST);
    float* statsf  = ws + OSTF;
    float* bn   = ws + OBN;
    int* deg  = (int*)(ws + ODEG);
    int* off  = (int*)(ws + OOFF);
    int* cnt  = (int*)(ws + OCNT);
    int2* elist = (int2*)(ws + OEL);

    // edge MLP + rp stats
    k_init<<<1, 64, 0, stream>>>(dstats);
    k_rp<<<(EE + 15) / 16, 256, 0, stream>>>(x, ei, rp, dstats);
    k_statsf<<<1, 1, 0, stream>>>(dstats, statsf);
    k_mlp<<<(EE + 255) / 256, 256, 0, stream>>>(ea, eW1, eb1, eW2, eb2, rp, statsf, out_e);

    // CSR build (edge_index is layer-invariant)
    k_zint<<<(NN + 255) / 256, 256, 0, stream>>>(deg, cnt);
    k_deg<<<(EE + 255) / 256, 256, 0, stream>>>(ei, deg);
    k_scan<<<1, 1024, 0, stream>>>(deg, off);
    k_scatter<<<(EE + 255) / 256, 256, 0, stream>>>(ei, off, cnt, elist);

    const float* xin = x;
    for (int l = 0; l < 3; ++l) {
        k_node<<<(NN + 255) / 256, 256, 0, stream>>>(xin,
            Wq + (size_t)l * 4096, bq + (size_t)l * 64,
            Wk + (size_t)l * 4096, bk + (size_t)l * 64,
            Wv + (size_t)l * 4096, bv + (size_t)l * 64,
            Wsk + (size_t)l * 4096, bsk + (size_t)l * 64,
            q, k, v, sk);
        float* conv = (l == 2) ? out_x : sk;   // in-place skip add for l<2 (same-element RMW only)
        k_edge<<<(NN + 3) / 4, 256, 0, stream>>>(off, elist, out_e,
            We + (size_t)l * 4096, q, k, v, sk, conv);
        if (l < 2) {
            k_zbn<<<1, 128, 0, stream>>>(bn);
            k_bnstat<<<1024, 256, 0, stream>>>(conv, bn);
            float* xout = (l == 0) ? bufA : bufB;
            k_bnln<<<(NN + 3) / 4, 256, 0, stream>>>(conv, xin, bn,
                bng + (size_t)l * 64, bnb + (size_t)l * 64,
                lng + (size_t)l * 64, lnb + (size_t)l * 64, xout);
            xin = xout;
        }
    }
}

// Round 3
// 1255.682 us; speedup vs baseline: 5.8293x; 1.5613x over previous
//
#include <hip/hip_runtime.h>
#include <cstdint>
#include <cstddef>

#define NN 50000
#define EE 500000
#define NPART 1024

// ---------------- workspace layout (float offsets) ----------------
static constexpr size_t NF   = (size_t)NN * 64;
static constexpr size_t OQ   = 0;
static constexpr size_t OKk  = OQ   + NF;
static constexpr size_t OV   = OKk  + NF;
static constexpr size_t OSK  = OV   + NF;
static constexpr size_t OBA  = OSK  + NF;
static constexpr size_t OBB  = OBA  + NF;
static constexpr size_t ORP  = OBB  + NF;                  // rp EE
static constexpr size_t OPART= ORP  + (size_t)EE;          // 1024*2 doubles = 4096 floats
static constexpr size_t OSTF = OPART+ 4096;                // statsf 2 floats
static constexpr size_t OBN  = OSTF + 2;                   // bn sums 128 floats
static constexpr size_t OI   = OBN  + 128;                 // int area
static constexpr size_t ODEG = OI;
static constexpr size_t OOFF = ODEG + NN;
static constexpr size_t OCNT = OOFF + NN + 2;
static constexpr size_t OEL  = OCNT + NN;                  // elist EE int2

// out-row(64) = xv(1x64) * W(64x64, LDS) + b(LDS)
__device__ __forceinline__ void gemv64(const float (&xv)[64],
                                       const float* __restrict__ sW,
                                       const float* __restrict__ sb,
                                       float* __restrict__ dst) {
    for (int jch = 0; jch < 4; ++jch) {
        float ov[16];
#pragma unroll
        for (int jj = 0; jj < 16; ++jj) ov[jj] = sb[jch * 16 + jj];
#pragma unroll
        for (int kk = 0; kk < 64; ++kk) {
            float xk = xv[kk];
            const float* wr = sW + kk * 64 + jch * 16;
#pragma unroll
            for (int jj = 0; jj < 16; ++jj) ov[jj] = fmaf(xk, wr[jj], ov[jj]);
        }
        float4* pd = reinterpret_cast<float4*>(dst + jch * 16);
        pd[0] = make_float4(ov[0], ov[1], ov[2], ov[3]);
        pd[1] = make_float4(ov[4], ov[5], ov[6], ov[7]);
        pd[2] = make_float4(ov[8], ov[9], ov[10], ov[11]);
        pd[3] = make_float4(ov[12], ov[13], ov[14], ov[15]);
    }
}

// ---------------- rp: 1 thread/edge, per-block partials, no global atomics ----------------
__global__ __launch_bounds__(256) void k_rp(const float* __restrict__ x,
                                            const int* __restrict__ ei,
                                            float* __restrict__ rp,
                                            double* __restrict__ partial) {
    int tid = threadIdx.x;
    size_t stride = (size_t)gridDim.x * 256;
    double c1 = 0.0, c2 = 0.0;
    for (size_t e = (size_t)blockIdx.x * 256 + tid; e < (size_t)EE; e += stride) {
        size_t r = (size_t)ei[e], c = (size_t)ei[EE + e];
        const float4* pa = reinterpret_cast<const float4*>(x + r * 64);
        const float4* pb = reinterpret_cast<const float4*>(x + c * 64);
        float s0 = 0.f, s1 = 0.f, s2 = 0.f, s3 = 0.f;
#pragma unroll
        for (int i = 0; i < 16; ++i) {
            float4 a = pa[i], b = pb[i];
            float dx = a.x - b.x, dy = a.y - b.y, dz = a.z - b.z, dw = a.w - b.w;
            s0 = fmaf(dx, dx, s0); s1 = fmaf(dy, dy, s1);
            s2 = fmaf(dz, dz, s2); s3 = fmaf(dw, dw, s3);
        }
        float rv = sqrtf((s0 + s1) + (s2 + s3));
        rp[e] = rv;
        c1 += (double)rv; c2 += (double)rv * (double)rv;
    }
    __shared__ double l1[256], l2[256];
    l1[tid] = c1; l2[tid] = c2;
    __syncthreads();
    for (int o = 128; o > 0; o >>= 1) {
        if (tid < o) { l1[tid] += l1[tid + o]; l2[tid] += l2[tid + o]; }
        __syncthreads();
    }
    if (tid == 0) { partial[blockIdx.x * 2] = l1[0]; partial[blockIdx.x * 2 + 1] = l2[0]; }
}

__global__ __launch_bounds__(256) void k_statsf(const double* __restrict__ partial,
                                                float* __restrict__ statsf) {
    __shared__ double l1[256], l2[256];
    int tid = threadIdx.x;
    double a = 0.0, b = 0.0;
    for (int i = tid; i < NPART; i += 256) { a += partial[2 * i]; b += partial[2 * i + 1]; }
    l1[tid] = a; l2[tid] = b;
    __syncthreads();
    for (int o = 128; o > 0; o >>= 1) {
        if (tid < o) { l1[tid] += l1[tid + o]; l2[tid] += l2[tid + o]; }
        __syncthreads();
    }
    if (tid == 0) {
        double s = l1[0], q = l2[0];
        double mean = s / (double)EE;
        double var = (q - (double)EE * mean * mean) / (double)(EE - 1);
        if (var < 0) var = 0;
        statsf[0] = (float)mean;
        statsf[1] = (float)(1.0 / (sqrt(var) + 1e-6));
    }
}

// ---------------- edge-encoder MLP ----------------
__global__ __launch_bounds__(256) void k_mlp(const float* __restrict__ ea,
                                             const float* __restrict__ W1, const float* __restrict__ b1,
                                             const float* __restrict__ W2, const float* __restrict__ b2,
                                             const float* __restrict__ rp, const float* __restrict__ statsf,
                                             float* __restrict__ eout) {
    __shared__ float sW1[4096], sW2[4096], sb1[64], sb2[64];
    int tid = threadIdx.x;
    for (int i = tid; i < 4096; i += 256) { sW1[i] = W1[i]; sW2[i] = W2[i]; }
    if (tid < 64) { sb1[tid] = b1[tid]; sb2[tid] = b2[tid]; }
    __syncthreads();
    size_t e = (size_t)blockIdx.x * 256 + tid;
    if (e >= (size_t)EE) return;

    float xv[64];
    const float4* px = reinterpret_cast<const float4*>(ea + e * 64);
#pragma unroll
    for (int i = 0; i < 16; ++i) {
        float4 t = px[i];
        xv[4 * i] = t.x; xv[4 * i + 1] = t.y; xv[4 * i + 2] = t.z; xv[4 * i + 3] = t.w;
    }
    float ov[64];
#pragma unroll
    for (int j = 0; j < 64; ++j) ov[j] = sb2[j];
    for (int ch = 0; ch < 4; ++ch) {
        float hc[16];
#pragma unroll
        for (int t = 0; t < 16; ++t) hc[t] = sb1[ch * 16 + t];
#pragma unroll
        for (int kk = 0; kk < 64; ++kk) {
            float xk = xv[kk];
            const float* wr = sW1 + kk * 64 + ch * 16;
#pragma unroll
            for (int t = 0; t < 16; ++t) hc[t] = fmaf(xk, wr[t], hc[t]);
        }
#pragma unroll
        for (int t = 0; t < 16; ++t) hc[t] = fmaxf(hc[t], 0.f);
#pragma unroll
        for (int t = 0; t < 16; ++t) {
            float hk = hc[t];
            const float* wr = sW2 + (ch * 16 + t) * 64;
#pragma unroll
            for (int j = 0; j < 64; ++j) ov[j] = fmaf(hk, wr[j], ov[j]);
        }
    }
    float rps = (rp[e] - statsf[0]) * statsf[1];
    float4* pd = reinterpret_cast<float4*>(eout + e * 64);
#pragma unroll
    for (int i = 0; i < 16; ++i)
        pd[i] = make_float4(ov[4 * i] + rps, ov[4 * i + 1] + rps, ov[4 * i + 2] + rps, ov[4 * i + 3] + rps);
}

// ---------------- CSR build ----------------
__global__ void k_zint(int* deg, int* cnt) {
    int i = blockIdx.x * 256 + threadIdx.x;
    if (i < NN) { deg[i] = 0; cnt[i] = 0; }
}

__global__ void k_deg(const int* __restrict__ ei, int* __restrict__ deg) {
    int e = blockIdx.x * 256 + threadIdx.x;
    if (e < EE) atomicAdd(&deg[ei[EE + e]], 1);
}

__global__ __launch_bounds__(1024) void k_scan(const int* __restrict__ deg, int* __restrict__ off) {
    __shared__ int part[1024];
    int t = threadIdx.x;
    const int chunk = (NN + 1023) / 1024;
    int lo = t * chunk, hi = min(lo + chunk, NN);
    int s = 0;
    for (int i = lo; i < hi; ++i) s += deg[i];
    part[t] = s;
    __syncthreads();
    for (int o = 1; o < 1024; o <<= 1) {
        int v = (t >= o) ? part[t - o] : 0;
        __syncthreads();
        part[t] += v;
        __syncthreads();
    }
    int base = (t == 0) ? 0 : part[t - 1];
    for (int i = lo; i < hi; ++i) { off[i] = base; base += deg[i]; }
    if (t == 0) off[NN] = EE;
}

__global__ void k_scatter(const int* __restrict__ ei, const int* __restrict__ off,
                          int* __restrict__ cnt, int2* __restrict__ elist) {
    int e = blockIdx.x * 256 + threadIdx.x;
    if (e >= EE) return;
    int r = ei[e], c = ei[EE + e];
    int pos = off[c] + atomicAdd(&cnt[c], 1);
    elist[pos] = make_int2(e, r);
}

// ---------------- node-side GEMVs ----------------
__global__ __launch_bounds__(256) void k_node(const float* __restrict__ xin,
                                              const float* __restrict__ Wq, const float* __restrict__ bq,
                                              const float* __restrict__ Wk, const float* __restrict__ bk,
                                              const float* __restrict__ Wv, const float* __restrict__ bv,
                                              const float* __restrict__ Wsk, const float* __restrict__ bsk,
                                              float* __restrict__ q, float* __restrict__ k,
                                              float* __restrict__ v, float* __restrict__ sk) {
    __shared__ float sA[4096], sB[4096], sba[64], sbb[64];
    int tid = threadIdx.x;
    size_t node = (size_t)blockIdx.x * 256 + tid;
    bool ok = node < (size_t)NN;
    float xv[64];
    if (ok) {
        const float4* px = reinterpret_cast<const float4*>(xin + node * 64);
#pragma unroll
        for (int i = 0; i < 16; ++i) {
            float4 t = px[i];
            xv[4 * i] = t.x; xv[4 * i + 1] = t.y; xv[4 * i + 2] = t.z; xv[4 * i + 3] = t.w;
        }
    }
    for (int i = tid; i < 4096; i += 256) { sA[i] = Wq[i]; sB[i] = Wk[i]; }
    if (tid < 64) { sba[tid] = bq[tid]; sbb[tid] = bk[tid]; }
    __syncthreads();
    if (ok) { gemv64(xv, sA, sba, q + node * 64); gemv64(xv, sB, sbb, k + node * 64); }
    __syncthreads();
    for (int i = tid; i < 4096; i += 256) { sA[i] = Wv[i]; sB[i] = Wsk[i]; }
    if (tid < 64) { sba[tid] = bv[tid]; sbb[tid] = bsk[tid]; }
    __syncthreads();
    if (ok) { gemv64(xv, sA, sba, v + node * 64); gemv64(xv, sB, sbb, sk + node * 64); }
}

// ---------------- fused per-destination attention (online softmax) ----------------
// one wave per destination node; lane l owns output column l.
// e-row read via wave-uniform scalar loads (readfirstlane'd edge id).
__global__ __launch_bounds__(256) void k_edge(const int* __restrict__ off,
                                              const int2* __restrict__ elist,
                                              const float* __restrict__ eptr,
                                              const float* __restrict__ Wep,
                                              const float* __restrict__ q,
                                              const float* __restrict__ kf,
                                              const float* __restrict__ vf,
                                              const float* __restrict__ skp,
                                              float* __restrict__ outb) {
    int lane = threadIdx.x & 63;
    size_t node = (size_t)blockIdx.x * 4 + (threadIdx.x >> 6);
    if (node >= (size_t)NN) return;

    float wcol[64];
#pragma unroll
    for (int kk = 0; kk < 64; ++kk) wcol[kk] = Wep[kk * 64 + lane];

    float qv = q[node * 64 + lane];
    int p0 = off[node], p1 = off[node + 1];

    float m = -INFINITY, s = 0.f, o = 0.f;
    if (p0 < p1) {
        int2 prn = elist[p0];
        for (int p = p0; p < p1; ++p) {
            int2 pr = prn;
            if (p + 1 < p1) prn = elist[p + 1];
            int eu = __builtin_amdgcn_readfirstlane(pr.x);
            int ru = __builtin_amdgcn_readfirstlane(pr.y);
            const float* __restrict__ er = eptr + (size_t)eu * 64;
            float kv = kf[(size_t)ru * 64 + lane];
            float vv = vf[(size_t)ru * 64 + lane];
            float e0 = 0.f, e1 = 0.f, e2 = 0.f, e3 = 0.f;
#pragma unroll
            for (int kk = 0; kk < 64; kk += 4) {
                e0 = fmaf(er[kk + 0], wcol[kk + 0], e0);
                e1 = fmaf(er[kk + 1], wcol[kk + 1], e1);
                e2 = fmaf(er[kk + 2], wcol[kk + 2], e2);
                e3 = fmaf(er[kk + 3], wcol[kk + 3], e3);
            }
            float ee = (e0 + e1) + (e2 + e3);
            float d = qv * (kv + ee);
            d += __shfl_xor(d, 1); d += __shfl_xor(d, 2);
            d += __shfl_xor(d, 4); d += __shfl_xor(d, 8);
            float alpha = d * 0.25f;
            float mn = fmaxf(m, alpha);
            float sc = __expf(m - mn);
            float pt = __expf(alpha - mn);
            s = s * sc + pt;
            o = o * sc + pt * (vv + ee);
            m = mn;
        }
    }
    outb[node * 64 + lane] = o / (s + 1e-16f) + skp[node * 64 + lane];
}

// ---------------- BN stats + BN/ReLU/residual/LN ----------------
__global__ void k_zbn(float* bn) {
    if (threadIdx.x < 128) bn[threadIdx.x] = 0.f;
}

__global__ __launch_bounds__(256) void k_bnstat(const float* __restrict__ conv, float* __restrict__ bn) {
    int tid = threadIdx.x;
    size_t idx0 = (size_t)blockIdx.x * 256 + tid;
    size_t stride = (size_t)gridDim.x * 256;
    float s = 0.f, ss = 0.f;
    for (size_t i = idx0; i < NF; i += stride) {
        float val = conv[i];
        s += val; ss += val * val;
    }
    __shared__ float l1[256], l2[256];
    l1[tid] = s; l2[tid] = ss;
    __syncthreads();
    if (tid < 64) {
        float a = l1[tid] + l1[tid + 64] + l1[tid + 128] + l1[tid + 192];
        float b = l2[tid] + l2[tid + 64] + l2[tid + 128] + l2[tid + 192];
        atomicAdd(bn + tid, a);
        atomicAdd(bn + 64 + tid, b);
    }
}

__global__ __launch_bounds__(256) void k_bnln(const float* __restrict__ conv,
                                              const float* __restrict__ xres,
                                              const float* __restrict__ bn,
                                              const float* __restrict__ g, const float* __restrict__ b,
                                              const float* __restrict__ lg, const float* __restrict__ lb,
                                              float* __restrict__ xout) {
    int tid = threadIdx.x;
    int lane = tid & 63;
    size_t row = (size_t)blockIdx.x * 4 + (tid >> 6);
    if (row >= (size_t)NN) return;
    float val = conv[row * 64 + lane];
    float mu = bn[lane] * (1.f / NN);
    float var = bn[64 + lane] * (1.f / NN) - mu * mu;
    float hn = (val - mu) * rsqrtf(var + 1e-5f) * g[lane] + b[lane];
    hn = fmaxf(hn, 0.f);
    float t = hn + xres[row * 64 + lane];
    float s = t, ss = t * t;
#pragma unroll
    for (int o = 32; o >= 1; o >>= 1) { s += __shfl_xor(s, o); ss += __shfl_xor(ss, o); }
    float mu2 = s * (1.f / 64.f);
    float var2 = ss * (1.f / 64.f) - mu2 * mu2;
    xout[row * 64 + lane] = (t - mu2) * rsqrtf(var2 + 1e-5f) * lg[lane] + lb[lane];
}

// ---------------- launch ----------------
extern "C" void kernel_launch(void* const* d_in, const int* in_sizes, int n_in,
                              void* d_out, int out_size, void* d_ws, size_t ws_size,
                              hipStream_t stream) {
    (void)in_sizes; (void)n_in; (void)out_size; (void)ws_size;
    const float* x   = (const float*)d_in[0];
    const int*   ei  = (const int*)d_in[1];
    const float* ea  = (const float*)d_in[2];
    const float* Wq  = (const float*)d_in[3];  const float* bq = (const float*)d_in[4];
    const float* Wk  = (const float*)d_in[5];  const float* bk = (const float*)d_in[6];
    const float* Wv  = (const float*)d_in[7];  const float* bv = (const float*)d_in[8];
    const float* We  = (const float*)d_in[9];
    const float* Wsk = (const float*)d_in[10]; const float* bsk = (const float*)d_in[11];
    const float* eW1 = (const float*)d_in[12]; const float* eb1 = (const float*)d_in[13];
    const float* eW2 = (const float*)d_in[14]; const float* eb2 = (const float*)d_in[15];
    const float* bng = (const float*)d_in[16]; const float* bnb = (const float*)d_in[17];
    const float* lng = (const float*)d_in[18]; const float* lnb = (const float*)d_in[19];

    float* ws = (float*)d_ws;
    float* out_x = (float*)d_out;
    float* out_e = out_x + NF;

    float* q    = ws + OQ;
    float* k    = ws + OKk;
    float* v    = ws + OV;
    float* sk   = ws + OSK;
    float* bufA = ws + OBA;
    float* bufB = ws + OBB;
    float* rp   = ws + ORP;
    double* partial = (double*)(ws + OPART);
    float* statsf   = ws + OSTF;
    float* bn   = ws + OBN;
    int* deg  = (int*)(ws + ODEG);
    int* off  = (int*)(ws + OOFF);
    int* cnt  = (int*)(ws + OCNT);
    int2* elist = (int2*)(ws + OEL);

    // rp + stats + edge MLP
    k_rp<<<NPART, 256, 0, stream>>>(x, ei, rp, partial);
    k_statsf<<<1, 256, 0, stream>>>(partial, statsf);
    k_mlp<<<(EE + 255) / 256, 256, 0, stream>>>(ea, eW1, eb1, eW2, eb2, rp, statsf, out_e);

    // CSR build (edge_index is layer-invariant)
    k_zint<<<(NN + 255) / 256, 256, 0, stream>>>(deg, cnt);
    k_deg<<<(EE + 255) / 256, 256, 0, stream>>>(ei, deg);
    k_scan<<<1, 1024, 0, stream>>>(deg, off);
    k_scatter<<<(EE + 255) / 256, 256, 0, stream>>>(ei, off, cnt, elist);

    const float* xin = x;
    for (int l = 0; l < 3; ++l) {
        k_node<<<(NN + 255) / 256, 256, 0, stream>>>(xin,
            Wq + (size_t)l * 4096, bq + (size_t)l * 64,
            Wk + (size_t)l * 4096, bk + (size_t)l * 64,
            Wv + (size_t)l * 4096, bv + (size_t)l * 64,
            Wsk + (size_t)l * 4096, bsk + (size_t)l * 64,
            q, k, v, sk);
        float* conv = (l == 2) ? out_x : sk;   // in-place skip add (same-element RMW only)
        k_edge<<<(NN + 3) / 4, 256, 0, stream>>>(off, elist, out_e,
            We + (size_t)l * 4096, q, k, v, sk, conv);
        if (l < 2) {
            k_zbn<<<1, 128, 0, stream>>>(bn);
            k_bnstat<<<1024, 256, 0, stream>>>(conv, bn);
            float* xout = (l == 0) ? bufA : bufB;
            k_bnln<<<(NN + 3) / 4, 256, 0, stream>>>(conv, xin, bn,
                bng + (size_t)l * 64, bnb + (size_t)l * 64,
                lng + (size_t)l * 64, lnb + (size_t)l * 64, xout);
            xin = xout;
        }
    }
}

// Round 4
// 1248.356 us; speedup vs baseline: 5.8635x; 1.0059x over previous
//
#include <hip/hip_runtime.h>
#include <cstdint>
#include <cstddef>

#define NN 50000
#define EE 500000
#define NPART 1024

// ---------------- workspace layout (float offsets) ----------------
static constexpr size_t NF   = (size_t)NN * 64;
static constexpr size_t OQ   = 0;
static constexpr size_t OKk  = OQ   + NF;
static constexpr size_t OV   = OKk  + NF;
static constexpr size_t OSK  = OV   + NF;
static constexpr size_t OBA  = OSK  + NF;
static constexpr size_t OBB  = OBA  + NF;
static constexpr size_t ORP  = OBB  + NF;                  // rp EE
static constexpr size_t OPART= ORP  + (size_t)EE;          // 1024*2 doubles
static constexpr size_t OSTF = OPART+ 4096;                // statsf 2 floats
static constexpr size_t OBN  = OSTF + 2;                   // bn sums 128 floats
static constexpr size_t OI   = OBN  + 128;                 // int area
static constexpr size_t ODEG = OI;
static constexpr size_t OOFF = ODEG + NN;
static constexpr size_t OCNT = OOFF + NN + 2;
static constexpr size_t OEL  = OCNT + NN;                  // elist EE int2

// out-row(64) = xv(1x64) * W(64x64, global, uniform scalar loads) + b
__device__ __forceinline__ void gemv64(const float (&xv)[64],
                                       const float* __restrict__ W,
                                       const float* __restrict__ b,
                                       float* __restrict__ dst) {
    for (int jch = 0; jch < 4; ++jch) {
        float ov[16];
#pragma unroll
        for (int jj = 0; jj < 16; ++jj) ov[jj] = b[jch * 16 + jj];
#pragma unroll
        for (int kk = 0; kk < 64; ++kk) {
            float xk = xv[kk];
            const float* wr = W + kk * 64 + jch * 16;
#pragma unroll
            for (int jj = 0; jj < 16; ++jj) ov[jj] = fmaf(xk, wr[jj], ov[jj]);
        }
        float4* pd = reinterpret_cast<float4*>(dst + jch * 16);
        pd[0] = make_float4(ov[0], ov[1], ov[2], ov[3]);
        pd[1] = make_float4(ov[4], ov[5], ov[6], ov[7]);
        pd[2] = make_float4(ov[8], ov[9], ov[10], ov[11]);
        pd[3] = make_float4(ov[12], ov[13], ov[14], ov[15]);
    }
}

// ---------------- rp ----------------
__global__ __launch_bounds__(256) void k_rp(const float* __restrict__ x,
                                            const int* __restrict__ ei,
                                            float* __restrict__ rp,
                                            double* __restrict__ partial) {
    int tid = threadIdx.x;
    size_t stride = (size_t)gridDim.x * 256;
    double c1 = 0.0, c2 = 0.0;
    for (size_t e = (size_t)blockIdx.x * 256 + tid; e < (size_t)EE; e += stride) {
        size_t r = (size_t)ei[e], c = (size_t)ei[EE + e];
        const float4* pa = reinterpret_cast<const float4*>(x + r * 64);
        const float4* pb = reinterpret_cast<const float4*>(x + c * 64);
        float s0 = 0.f, s1 = 0.f, s2 = 0.f, s3 = 0.f;
#pragma unroll
        for (int i = 0; i < 16; ++i) {
            float4 a = pa[i], b = pb[i];
            float dx = a.x - b.x, dy = a.y - b.y, dz = a.z - b.z, dw = a.w - b.w;
            s0 = fmaf(dx, dx, s0); s1 = fmaf(dy, dy, s1);
            s2 = fmaf(dz, dz, s2); s3 = fmaf(dw, dw, s3);
        }
        float rv = sqrtf((s0 + s1) + (s2 + s3));
        rp[e] = rv;
        c1 += (double)rv; c2 += (double)rv * (double)rv;
    }
    __shared__ double l1[256], l2[256];
    l1[tid] = c1; l2[tid] = c2;
    __syncthreads();
    for (int o = 128; o > 0; o >>= 1) {
        if (tid < o) { l1[tid] += l1[tid + o]; l2[tid] += l2[tid + o]; }
        __syncthreads();
    }
    if (tid == 0) { partial[blockIdx.x * 2] = l1[0]; partial[blockIdx.x * 2 + 1] = l2[0]; }
}

__global__ __launch_bounds__(256) void k_statsf(const double* __restrict__ partial,
                                                float* __restrict__ statsf) {
    __shared__ double l1[256], l2[256];
    int tid = threadIdx.x;
    double a = 0.0, b = 0.0;
    for (int i = tid; i < NPART; i += 256) { a += partial[2 * i]; b += partial[2 * i + 1]; }
    l1[tid] = a; l2[tid] = b;
    __syncthreads();
    for (int o = 128; o > 0; o >>= 1) {
        if (tid < o) { l1[tid] += l1[tid + o]; l2[tid] += l2[tid + o]; }
        __syncthreads();
    }
    if (tid == 0) {
        double s = l1[0], q = l2[0];
        double mean = s / (double)EE;
        double var = (q - (double)EE * mean * mean) / (double)(EE - 1);
        if (var < 0) var = 0;
        statsf[0] = (float)mean;
        statsf[1] = (float)(1.0 / (sqrt(var) + 1e-6));
    }
}

// ---------------- edge-encoder MLP (weights via uniform scalar loads) ----------------
__global__ __launch_bounds__(256) void k_mlp(const float* __restrict__ ea,
                                             const float* __restrict__ W1, const float* __restrict__ b1,
                                             const float* __restrict__ W2, const float* __restrict__ b2,
                                             const float* __restrict__ rp, const float* __restrict__ statsf,
                                             float* __restrict__ eout) {
    size_t e = (size_t)blockIdx.x * 256 + threadIdx.x;
    if (e >= (size_t)EE) return;

    float xv[64];
    const float4* px = reinterpret_cast<const float4*>(ea + e * 64);
#pragma unroll
    for (int i = 0; i < 16; ++i) {
        float4 t = px[i];
        xv[4 * i] = t.x; xv[4 * i + 1] = t.y; xv[4 * i + 2] = t.z; xv[4 * i + 3] = t.w;
    }
    float ov[64];
#pragma unroll
    for (int j = 0; j < 64; ++j) ov[j] = b2[j];
    for (int ch = 0; ch < 4; ++ch) {
        float hc[16];
#pragma unroll
        for (int t = 0; t < 16; ++t) hc[t] = b1[ch * 16 + t];
#pragma unroll
        for (int kk = 0; kk < 64; ++kk) {
            float xk = xv[kk];
            const float* wr = W1 + kk * 64 + ch * 16;
#pragma unroll
            for (int t = 0; t < 16; ++t) hc[t] = fmaf(xk, wr[t], hc[t]);
        }
#pragma unroll
        for (int t = 0; t < 16; ++t) hc[t] = fmaxf(hc[t], 0.f);
#pragma unroll
        for (int t = 0; t < 16; ++t) {
            float hk = hc[t];
            const float* wr = W2 + (ch * 16 + t) * 64;
#pragma unroll
            for (int j = 0; j < 64; ++j) ov[j] = fmaf(hk, wr[j], ov[j]);
        }
    }
    float rps = (rp[e] - statsf[0]) * statsf[1];
    float4* pd = reinterpret_cast<float4*>(eout + e * 64);
#pragma unroll
    for (int i = 0; i < 16; ++i)
        pd[i] = make_float4(ov[4 * i] + rps, ov[4 * i + 1] + rps, ov[4 * i + 2] + rps, ov[4 * i + 3] + rps);
}

// ---------------- CSR build ----------------
__global__ void k_zint(int* deg, int* cnt) {
    int i = blockIdx.x * 256 + threadIdx.x;
    if (i < NN) { deg[i] = 0; cnt[i] = 0; }
}

__global__ void k_deg(const int* __restrict__ ei, int* __restrict__ deg) {
    int e = blockIdx.x * 256 + threadIdx.x;
    if (e < EE) atomicAdd(&deg[ei[EE + e]], 1);
}

__global__ __launch_bounds__(1024) void k_scan(const int* __restrict__ deg, int* __restrict__ off) {
    __shared__ int part[1024];
    int t = threadIdx.x;
    const int chunk = (NN + 1023) / 1024;
    int lo = t * chunk, hi = min(lo + chunk, NN);
    int s = 0;
    for (int i = lo; i < hi; ++i) s += deg[i];
    part[t] = s;
    __syncthreads();
    for (int o = 1; o < 1024; o <<= 1) {
        int v = (t >= o) ? part[t - o] : 0;
        __syncthreads();
        part[t] += v;
        __syncthreads();
    }
    int base = (t == 0) ? 0 : part[t - 1];
    for (int i = lo; i < hi; ++i) { off[i] = base; base += deg[i]; }
    if (t == 0) off[NN] = EE;
}

__global__ void k_scatter(const int* __restrict__ ei, const int* __restrict__ off,
                          int* __restrict__ cnt, int2* __restrict__ elist) {
    int e = blockIdx.x * 256 + threadIdx.x;
    if (e >= EE) return;
    int r = ei[e], c = ei[EE + e];
    int pos = off[c] + atomicAdd(&cnt[c], 1);
    elist[pos] = make_int2(e, r);
}

// ---------------- node-side GEMVs (weights via uniform scalar loads) ----------------
__global__ __launch_bounds__(256) void k_node(const float* __restrict__ xin,
                                              const float* __restrict__ Wq, const float* __restrict__ bq,
                                              const float* __restrict__ Wk, const float* __restrict__ bk,
                                              const float* __restrict__ Wv, const float* __restrict__ bv,
                                              const float* __restrict__ Wsk, const float* __restrict__ bsk,
                                              float* __restrict__ q, float* __restrict__ k,
                                              float* __restrict__ v, float* __restrict__ sk) {
    size_t node = (size_t)blockIdx.x * 256 + threadIdx.x;
    if (node >= (size_t)NN) return;
    float xv[64];
    const float4* px = reinterpret_cast<const float4*>(xin + node * 64);
#pragma unroll
    for (int i = 0; i < 16; ++i) {
        float4 t = px[i];
        xv[4 * i] = t.x; xv[4 * i + 1] = t.y; xv[4 * i + 2] = t.z; xv[4 * i + 3] = t.w;
    }
    gemv64(xv, Wq, bq, q + node * 64);
    gemv64(xv, Wk, bk, k + node * 64);
    gemv64(xv, Wv, bv, v + node * 64);
    gemv64(xv, Wsk, bsk, sk + node * 64);
}

// ---------------- fused per-destination attention (online softmax, 4-edge batches) ----------------
__global__ __launch_bounds__(256) void k_edge(const int* __restrict__ off,
                                              const int2* __restrict__ elist,
                                              const float* __restrict__ eptr,
                                              const float* __restrict__ Wep,
                                              const float* __restrict__ q,
                                              const float* __restrict__ kf,
                                              const float* __restrict__ vf,
                                              const float* __restrict__ skp,
                                              float* __restrict__ outb) {
    int lane = threadIdx.x & 63;
    size_t node = (size_t)blockIdx.x * 4 + (threadIdx.x >> 6);
    if (node >= (size_t)NN) return;

    float wcol[64];
#pragma unroll
    for (int kk = 0; kk < 64; ++kk) wcol[kk] = Wep[kk * 64 + lane];

    float qv = q[node * 64 + lane];
    int p0 = off[node], p1 = off[node + 1];

    float m = -INFINITY, s = 0.f, o = 0.f;
    int p = p0;
    for (; p + 4 <= p1; p += 4) {
        int2 q0 = elist[p], q1 = elist[p + 1], q2 = elist[p + 2], q3 = elist[p + 3];
        int eu0 = __builtin_amdgcn_readfirstlane(q0.x);
        int ru0 = __builtin_amdgcn_readfirstlane(q0.y);
        int eu1 = __builtin_amdgcn_readfirstlane(q1.x);
        int ru1 = __builtin_amdgcn_readfirstlane(q1.y);
        int eu2 = __builtin_amdgcn_readfirstlane(q2.x);
        int ru2 = __builtin_amdgcn_readfirstlane(q2.y);
        int eu3 = __builtin_amdgcn_readfirstlane(q3.x);
        int ru3 = __builtin_amdgcn_readfirstlane(q3.y);
        const float* __restrict__ er0 = eptr + (size_t)eu0 * 64;
        const float* __restrict__ er1 = eptr + (size_t)eu1 * 64;
        const float* __restrict__ er2 = eptr + (size_t)eu2 * 64;
        const float* __restrict__ er3 = eptr + (size_t)eu3 * 64;
        float kv0 = kf[(size_t)ru0 * 64 + lane];
        float kv1 = kf[(size_t)ru1 * 64 + lane];
        float kv2 = kf[(size_t)ru2 * 64 + lane];
        float kv3 = kf[(size_t)ru3 * 64 + lane];
        float vv0 = vf[(size_t)ru0 * 64 + lane];
        float vv1 = vf[(size_t)ru1 * 64 + lane];
        float vv2 = vf[(size_t)ru2 * 64 + lane];
        float vv3 = vf[(size_t)ru3 * 64 + lane];
        float ee0 = 0.f, ee1 = 0.f, ee2 = 0.f, ee3 = 0.f;
#pragma unroll
        for (int kk = 0; kk < 64; ++kk) {
            float w = wcol[kk];
            ee0 = fmaf(er0[kk], w, ee0);
            ee1 = fmaf(er1[kk], w, ee1);
            ee2 = fmaf(er2[kk], w, ee2);
            ee3 = fmaf(er3[kk], w, ee3);
        }
        float d0 = qv * (kv0 + ee0);
        float d1 = qv * (kv1 + ee1);
        float d2 = qv * (kv2 + ee2);
        float d3 = qv * (kv3 + ee3);
        d0 += __shfl_xor(d0, 1); d1 += __shfl_xor(d1, 1);
        d2 += __shfl_xor(d2, 1); d3 += __shfl_xor(d3, 1);
        d0 += __shfl_xor(d0, 2); d1 += __shfl_xor(d1, 2);
        d2 += __shfl_xor(d2, 2); d3 += __shfl_xor(d3, 2);
        d0 += __shfl_xor(d0, 4); d1 += __shfl_xor(d1, 4);
        d2 += __shfl_xor(d2, 4); d3 += __shfl_xor(d3, 4);
        d0 += __shfl_xor(d0, 8); d1 += __shfl_xor(d1, 8);
        d2 += __shfl_xor(d2, 8); d3 += __shfl_xor(d3, 8);
        float a0 = d0 * 0.25f, a1 = d1 * 0.25f, a2 = d2 * 0.25f, a3 = d3 * 0.25f;
        float mn = fmaxf(fmaxf(m, fmaxf(a0, a1)), fmaxf(a2, a3));
        float sc = __expf(m - mn);
        float p0e = __expf(a0 - mn), p1e = __expf(a1 - mn);
        float p2e = __expf(a2 - mn), p3e = __expf(a3 - mn);
        s = s * sc + ((p0e + p1e) + (p2e + p3e));
        float ot = fmaf(p0e, vv0 + ee0, p1e * (vv1 + ee1));
        ot = fmaf(p2e, vv2 + ee2, ot);
        ot = fmaf(p3e, vv3 + ee3, ot);
        o = o * sc + ot;
        m = mn;
    }
    for (; p < p1; ++p) {
        int2 pr = elist[p];
        int eu = __builtin_amdgcn_readfirstlane(pr.x);
        int ru = __builtin_amdgcn_readfirstlane(pr.y);
        const float* __restrict__ er = eptr + (size_t)eu * 64;
        float kv = kf[(size_t)ru * 64 + lane];
        float vv = vf[(size_t)ru * 64 + lane];
        float e0 = 0.f, e1 = 0.f, e2 = 0.f, e3 = 0.f;
#pragma unroll
        for (int kk = 0; kk < 64; kk += 4) {
            e0 = fmaf(er[kk + 0], wcol[kk + 0], e0);
            e1 = fmaf(er[kk + 1], wcol[kk + 1], e1);
            e2 = fmaf(er[kk + 2], wcol[kk + 2], e2);
            e3 = fmaf(er[kk + 3], wcol[kk + 3], e3);
        }
        float ee = (e0 + e1) + (e2 + e3);
        float d = qv * (kv + ee);
        d += __shfl_xor(d, 1); d += __shfl_xor(d, 2);
        d += __shfl_xor(d, 4); d += __shfl_xor(d, 8);
        float alpha = d * 0.25f;
        float mn = fmaxf(m, alpha);
        float sc = __expf(m - mn);
        float pt = __expf(alpha - mn);
        s = s * sc + pt;
        o = o * sc + pt * (vv + ee);
        m = mn;
    }
    outb[node * 64 + lane] = o / (s + 1e-16f) + skp[node * 64 + lane];
}

// ---------------- BN stats + BN/ReLU/residual/LN ----------------
__global__ void k_zbn(float* bn) {
    if (threadIdx.x < 128) bn[threadIdx.x] = 0.f;
}

__global__ __launch_bounds__(256) void k_bnstat(const float* __restrict__ conv, float* __restrict__ bn) {
    int tid = threadIdx.x;
    size_t idx0 = (size_t)blockIdx.x * 256 + tid;
    size_t stride = (size_t)gridDim.x * 256;
    float s = 0.f, ss = 0.f;
    for (size_t i = idx0; i < NF; i += stride) {
        float val = conv[i];
        s += val; ss += val * val;
    }
    __shared__ float l1[256], l2[256];
    l1[tid] = s; l2[tid] = ss;
    __syncthreads();
    if (tid < 64) {
        float a = l1[tid] + l1[tid + 64] + l1[tid + 128] + l1[tid + 192];
        float b = l2[tid] + l2[tid + 64] + l2[tid + 128] + l2[tid + 192];
        atomicAdd(bn + tid, a);
        atomicAdd(bn + 64 + tid, b);
    }
}

__global__ __launch_bounds__(256) void k_bnln(const float* __restrict__ conv,
                                              const float* __restrict__ xres,
                                              const float* __restrict__ bn,
                                              const float* __restrict__ g, const float* __restrict__ b,
                                              const float* __restrict__ lg, const float* __restrict__ lb,
                                              float* __restrict__ xout) {
    int tid = threadIdx.x;
    int lane = tid & 63;
    size_t row = (size_t)blockIdx.x * 4 + (tid >> 6);
    if (row >= (size_t)NN) return;
    float val = conv[row * 64 + lane];
    float mu = bn[lane] * (1.f / NN);
    float var = bn[64 + lane] * (1.f / NN) - mu * mu;
    float hn = (val - mu) * rsqrtf(var + 1e-5f) * g[lane] + b[lane];
    hn = fmaxf(hn, 0.f);
    float t = hn + xres[row * 64 + lane];
    float s = t, ss = t * t;
#pragma unroll
    for (int o = 32; o >= 1; o >>= 1) { s += __shfl_xor(s, o); ss += __shfl_xor(ss, o); }
    float mu2 = s * (1.f / 64.f);
    float var2 = ss * (1.f / 64.f) - mu2 * mu2;
    xout[row * 64 + lane] = (t - mu2) * rsqrtf(var2 + 1e-5f) * lg[lane] + lb[lane];
}

// ---------------- launch ----------------
extern "C" void kernel_launch(void* const* d_in, const int* in_sizes, int n_in,
                              void* d_out, int out_size, void* d_ws, size_t ws_size,
                              hipStream_t stream) {
    (void)in_sizes; (void)n_in; (void)out_size; (void)ws_size;
    const float* x   = (const float*)d_in[0];
    const int*   ei  = (const int*)d_in[1];
    const float* ea  = (const float*)d_in[2];
    const float* Wq  = (const float*)d_in[3];  const float* bq = (const float*)d_in[4];
    const float* Wk  = (const float*)d_in[5];  const float* bk = (const float*)d_in[6];
    const float* Wv  = (const float*)d_in[7];  const float* bv = (const float*)d_in[8];
    const float* We  = (const float*)d_in[9];
    const float* Wsk = (const float*)d_in[10]; const float* bsk = (const float*)d_in[11];
    const float* eW1 = (const float*)d_in[12]; const float* eb1 = (const float*)d_in[13];
    const float* eW2 = (const float*)d_in[14]; const float* eb2 = (const float*)d_in[15];
    const float* bng = (const float*)d_in[16]; const float* bnb = (const float*)d_in[17];
    const float* lng = (const float*)d_in[18]; const float* lnb = (const float*)d_in[19];

    float* ws = (float*)d_ws;
    float* out_x = (float*)d_out;
    float* out_e = out_x + NF;

    float* q    = ws + OQ;
    float* k    = ws + OKk;
    float* v    = ws + OV;
    float* sk   = ws + OSK;
    float* bufA = ws + OBA;
    float* bufB = ws + OBB;
    float* rp   = ws + ORP;
    double* partial = (double*)(ws + OPART);
    float* statsf   = ws + OSTF;
    float* bn   = ws + OBN;
    int* deg  = (int*)(ws + ODEG);
    int* off  = (int*)(ws + OOFF);
    int* cnt  = (int*)(ws + OCNT);
    int2* elist = (int2*)(ws + OEL);

    k_rp<<<NPART, 256, 0, stream>>>(x, ei, rp, partial);
    k_statsf<<<1, 256, 0, stream>>>(partial, statsf);
    k_mlp<<<(EE + 255) / 256, 256, 0, stream>>>(ea, eW1, eb1, eW2, eb2, rp, statsf, out_e);

    k_zint<<<(NN + 255) / 256, 256, 0, stream>>>(deg, cnt);
    k_deg<<<(EE + 255) / 256, 256, 0, stream>>>(ei, deg);
    k_scan<<<1, 1024, 0, stream>>>(deg, off);
    k_scatter<<<(EE + 255) / 256, 256, 0, stream>>>(ei, off, cnt, elist);

    const float* xin = x;
    for (int l = 0; l < 3; ++l) {
        k_node<<<(NN + 255) / 256, 256, 0, stream>>>(xin,
            Wq + (size_t)l * 4096, bq + (size_t)l * 64,
            Wk + (size_t)l * 4096, bk + (size_t)l * 64,
            Wv + (size_t)l * 4096, bv + (size_t)l * 64,
            Wsk + (size_t)l * 4096, bsk + (size_t)l * 64,
            q, k, v, sk);
        float* conv = (l == 2) ? out_x : sk;   // in-place skip add (same-element RMW only)
        k_edge<<<(NN + 3) / 4, 256, 0, stream>>>(off, elist, out_e,
            We + (size_t)l * 4096, q, k, v, sk, conv);
        if (l < 2) {
            k_zbn<<<1, 128, 0, stream>>>(bn);
            k_bnstat<<<1024, 256, 0, stream>>>(conv, bn);
            float* xout = (l == 0) ? bufA : bufB;
            k_bnln<<<(NN + 3) / 4, 256, 0, stream>>>(conv, xin, bn,
                bng + (size_t)l * 64, bnb + (size_t)l * 64,
                lng + (size_t)l * 64, lnb + (size_t)l * 64, xout);
            xin = xout;
        }
    }
}